// Round 8
// baseline (334.878 us; speedup 1.0000x reference)
//
#include <hip/hip_runtime.h>
#include <hip/hip_fp16.h>
#include <math.h>

#define N_NODES 50000
#define N_EDGES 400000
#define NUM_GRAPHS 64
#define NSCAN_BLK ((N_NODES + 1023) / 1024)   // 49

// ---------------------------------------------------------------------------
// NNConv via piecewise-linear collapse + dst-CSR (atomic-free aggregation).
//   relu(a*w1_j+b1_j) is piecewise-linear in scalar a: 10 thresholds t_j split
//   R into <=11 intervals k. Per node/interval: A_k[n,o] = sum_{j act} w1_j*P[n,j,o],
//   Bt_k[n,o] = sum_{j act} b1_j*P[n,j,o] + Q[n,o]  (P,Q = node GEMM factors).
//   => msg[e,o] = a_e * A_k[src,o] + Bt_k[src,o]     (EXACT, any w1/b1/a)
// Tables tab1[n][11][16] / tab2[n][11][32] of half2{A,Bt} (one 64/128B line/row).
// Edges counting-sorted by dst; per-dst segment accumulated in registers ->
// single store (NO atomics). Node finalize (mean + root + bias + ELU) fused.
// ---------------------------------------------------------------------------

// thresholds + active-set masks for both layers (tiny, 1 thread)
__global__ void k_thr(const float* __restrict__ w1a, const float* __restrict__ b1a,
                      const float* __restrict__ w1b, const float* __restrict__ b1b,
                      float* __restrict__ T, int* __restrict__ M) {
    if (threadIdx.x != 0 || blockIdx.x != 0) return;
    for (int layer = 0; layer < 2; layer++) {
        const float* w1 = layer ? w1b : w1a;
        const float* b1 = layer ? b1b : b1a;
        float t[10]; int idx[10];
        for (int j = 0; j < 10; j++) {
            float w = w1[j];
            t[j] = (w != 0.f) ? (-b1[j] / w) : INFINITY;  // w==0: never crossed
            idx[j] = j;
        }
        // insertion sort by t
        for (int i = 1; i < 10; i++) {
            float tv = t[i]; int iv = idx[i]; int k = i - 1;
            while (k >= 0 && t[k] > tv) { t[k + 1] = t[k]; idx[k + 1] = idx[k]; k--; }
            t[k + 1] = tv; idx[k + 1] = iv;
        }
        int pos[10];
        for (int k = 0; k < 10; k++) pos[idx[k]] = k;
        for (int k = 0; k < 10; k++) T[layer * 10 + k] = t[k];
        for (int kap = 0; kap <= 10; kap++) {
            int m = 0;
            for (int j = 0; j < 10; j++) {
                float w = w1[j];
                bool act = (w > 0.f) ? (pos[j] < kap)
                         : (w < 0.f) ? (pos[j] >= kap)
                         : (b1[j] > 0.f);
                if (act) m |= (1 << j);
            }
            M[layer * 11 + kap] = m;
        }
    }
}

__global__ __launch_bounds__(256) void k0_hist(const int* __restrict__ dst,
        int* __restrict__ cntd) {
    int e = blockIdx.x * 256 + threadIdx.x;
    if (e < N_EDGES) atomicAdd(cntd + dst[e], 1);
}

// hierarchical scan A: per-block scan + block totals; writes roff AND woff
__global__ __launch_bounds__(1024) void k0_scanA(const int* __restrict__ cntd,
        int* __restrict__ roff, int* __restrict__ woff, int* __restrict__ bsum) {
    __shared__ int tmp[1024];
    int b = blockIdx.x, t = threadIdx.x;
    int n = b * 1024 + t;
    int v = (n < N_NODES) ? cntd[n] : 0;
    tmp[t] = v;
    __syncthreads();
    for (int off = 1; off < 1024; off <<= 1) {
        int add = (t >= off) ? tmp[t - off] : 0;
        __syncthreads();
        tmp[t] += add;
        __syncthreads();
    }
    if (n < N_NODES) { int ex = tmp[t] - v; roff[n] = ex; woff[n] = ex; }
    if (t == 1023) bsum[b] = tmp[1023];
}

__global__ __launch_bounds__(1024) void k0_scanB(const int* __restrict__ bsum,
        int* __restrict__ roff, int* __restrict__ woff) {
    __shared__ int boff;
    int b = blockIdx.x, t = threadIdx.x;
    if (t == 0) {
        int s = 0;
        for (int i = 0; i < b; i++) s += bsum[i];
        boff = s;
    }
    __syncthreads();
    int n = b * 1024 + t;
    if (n < N_NODES) { roff[n] += boff; woff[n] += boff; }
}

// scatter by dst; store row ids (src*11+kappa) for both layers + edge attr
__global__ __launch_bounds__(256) void k0_scatter(const int* __restrict__ src,
        const int* __restrict__ dst, const float* __restrict__ ea,
        const float* __restrict__ T, int* __restrict__ woff,
        int* __restrict__ sse1, int* __restrict__ sse2, float* __restrict__ sea) {
    int e = blockIdx.x * 256 + threadIdx.x;
    if (e >= N_EDGES) return;
    int s = src[e], d = dst[e];
    float a = ea[e];
    int k1 = 0, k2 = 0;
#pragma unroll
    for (int j = 0; j < 10; j++) {
        k1 += (T[j] < a);
        k2 += (T[10 + j] < a);
    }
    int pos = atomicAdd(woff + d, 1);
    sse1[pos] = s * 11 + k1;
    sse2[pos] = s * 11 + k2;
    sea[pos] = a;
}

// layer-1 node factors -> interval table tab1[n][11][16] half2{A,Bt}; R1 = x@root+bias
__global__ __launch_bounds__(256) void k1_p1(const float* __restrict__ x,
        const float* __restrict__ w2, const float* __restrict__ b2,
        const float* __restrict__ root, const float* __restrict__ w1,
        const float* __restrict__ b1, const float* __restrict__ bias1,
        const int* __restrict__ M, __half2* __restrict__ tab1,
        float* __restrict__ R1) {
    __shared__ float Wl[32][192];   // [i][m*16+o]
    __shared__ float xl[16][32];
    __shared__ float w1l[10], b1l[10];
    __shared__ int ml[11];
    int t = threadIdx.x;
    for (int idx = t; idx < 32 * 192; idx += 256) {
        int i = idx / 192, c = idx % 192;
        int m = c >> 4, o = c & 15;
        float w;
        if (m < 10)       w = w2[m * 512 + i * 16 + o];
        else if (m == 10) w = b2[i * 16 + o];
        else              w = root[i * 16 + o];
        Wl[i][c] = w;
    }
    if (t < 10) { w1l[t] = w1[t]; b1l[t] = b1[t]; }
    if (t < 11) ml[t] = M[t];
    int n0 = blockIdx.x * 16;
    for (int idx = t; idx < 16 * 32; idx += 256) {
        int nl = idx >> 5, i = idx & 31;
        int n = n0 + nl;
        xl[nl][i] = (n < N_NODES) ? x[n * 32 + i] : 0.f;
    }
    __syncthreads();
    int nl = t >> 4, o = t & 15;
    int n = n0 + nl;
    if (n >= N_NODES) return;
    float acc[12];
#pragma unroll
    for (int m = 0; m < 12; m++) acc[m] = 0.f;
#pragma unroll
    for (int i = 0; i < 32; i++) {
        float xv = xl[nl][i];
#pragma unroll
        for (int m = 0; m < 12; m++) acc[m] += xv * Wl[i][m * 16 + o];
    }
#pragma unroll
    for (int kap = 0; kap <= 10; kap++) {
        int m = ml[kap];
        float A = 0.f, B = acc[10];
#pragma unroll
        for (int j = 0; j < 10; j++) {
            float f = ((m >> j) & 1) ? 1.f : 0.f;
            A += f * w1l[j] * acc[j];
            B += f * b1l[j] * acc[j];
        }
        tab1[((size_t)(n * 11 + kap)) * 16 + o] = __floats2half2_rn(A, B);
    }
    R1[n * 16 + o] = acc[11] + bias1[o];
}

// layer-1 edges (dst-CSR): 16 dst/block x 16 lanes; register accumulate, fused ELU
__global__ __launch_bounds__(256) void k2_edge1(const __half2* __restrict__ tab1,
        const int* __restrict__ roff, const int* __restrict__ sse1,
        const float* __restrict__ sea, const float* __restrict__ R1,
        float* __restrict__ h1) {
    int t = threadIdx.x;
    int d = blockIdx.x * 16 + (t >> 4);
    int o = t & 15;
    if (d >= N_NODES) return;
    int start = roff[d];
    int end = (d == N_NODES - 1) ? N_EDGES : roff[d + 1];
    float acc = 0.f;
    for (int p = start; p < end; ++p) {
        int row = sse1[p];
        float a = sea[p];
        float2 f = __half22float2(tab1[(size_t)row * 16 + o]);
        acc += a * f.x + f.y;
    }
    int deg = end - start;
    float c = (float)(deg > 0 ? deg : 1);
    float v = acc / c + R1[d * 16 + o];
    h1[d * 16 + o] = v > 0.f ? v : expm1f(v);
}

// layer-2 node factors from h1 -> tab2[n][11][32]; R2 = h1@root+bias2
__global__ __launch_bounds__(256) void k4_p2(const float* __restrict__ h1,
        const float* __restrict__ w2, const float* __restrict__ b2,
        const float* __restrict__ root, const float* __restrict__ w1,
        const float* __restrict__ b1, const float* __restrict__ bias2,
        const int* __restrict__ M, __half2* __restrict__ tab2,
        float* __restrict__ R2) {
    __shared__ float Wl[16][384];   // [i][m*32+o]
    __shared__ float hl[8][16];
    __shared__ float w1l[10], b1l[10];
    __shared__ int ml[11];
    int t = threadIdx.x;
    for (int idx = t; idx < 16 * 384; idx += 256) {
        int i = idx / 384, c = idx % 384;
        int m = c >> 5, o = c & 31;
        float w;
        if (m < 10)       w = w2[m * 512 + i * 32 + o];
        else if (m == 10) w = b2[i * 32 + o];
        else              w = root[i * 32 + o];
        Wl[i][c] = w;
    }
    if (t < 10) { w1l[t] = w1[t]; b1l[t] = b1[t]; }
    if (t < 11) ml[t] = M[11 + t];
    int n0 = blockIdx.x * 8;
    if (t < 128) {
        int nl = t >> 4, i = t & 15;
        int n = n0 + nl;
        hl[nl][i] = (n < N_NODES) ? h1[n * 16 + i] : 0.f;
    }
    __syncthreads();
    int nl = t >> 5, o = t & 31;
    int n = n0 + nl;
    if (n >= N_NODES) return;
    float acc[12];
#pragma unroll
    for (int m = 0; m < 12; m++) acc[m] = 0.f;
#pragma unroll
    for (int i = 0; i < 16; i++) {
        float hv = hl[nl][i];
#pragma unroll
        for (int m = 0; m < 12; m++) acc[m] += hv * Wl[i][m * 32 + o];
    }
#pragma unroll
    for (int kap = 0; kap <= 10; kap++) {
        int m = ml[kap];
        float A = 0.f, B = acc[10];
#pragma unroll
        for (int j = 0; j < 10; j++) {
            float f = ((m >> j) & 1) ? 1.f : 0.f;
            A += f * w1l[j] * acc[j];
            B += f * b1l[j] * acc[j];
        }
        tab2[((size_t)(n * 11 + kap)) * 32 + o] = __floats2half2_rn(A, B);
    }
    R2[(size_t)n * 32 + o] = acc[11] + bias2[o];
}

// layer-2 edges (dst-CSR): 8 dst/block x 32 lanes; fused ELU -> h2
__global__ __launch_bounds__(256) void k5_edge2(const __half2* __restrict__ tab2,
        const int* __restrict__ roff, const int* __restrict__ sse2,
        const float* __restrict__ sea, const float* __restrict__ R2,
        float* __restrict__ h2) {
    int t = threadIdx.x;
    int d = blockIdx.x * 8 + (t >> 5);
    int o = t & 31;
    if (d >= N_NODES) return;
    int start = roff[d];
    int end = (d == N_NODES - 1) ? N_EDGES : roff[d + 1];
    float acc = 0.f;
    for (int p = start; p < end; ++p) {
        int row = sse2[p];
        float a = sea[p];
        float2 f = __half22float2(tab2[(size_t)row * 32 + o]);
        acc += a * f.x + f.y;
    }
    int deg = end - start;
    float c = (float)(deg > 0 ? deg : 1);
    float v = acc / c + R2[(size_t)d * 32 + o];
    h2[(size_t)d * 32 + o] = v > 0.f ? v : expm1f(v);
}

// pooling partials: 512 blocks, register accumulate per graph run, atomic on change
__global__ __launch_bounds__(256) void k6_partial(const float* __restrict__ h2,
        const int* __restrict__ batch, float* __restrict__ gsum) {
    const int NB = 512;
    const int chunk = (N_NODES + NB - 1) / NB;   // 98
    int begin = blockIdx.x * chunk;
    int end = begin + chunk;
    if (end > N_NODES) end = N_NODES;
    int t = threadIdx.x;
    int o = t & 31, ch = t >> 5;
    float acc = 0.f;
    int cur_g = -1;
    for (int n = begin + ch; n < end; n += 8) {
        int g = batch[n];
        float v = h2[(size_t)n * 32 + o];
        if (g != cur_g) {
            if (cur_g >= 0) atomicAdd(gsum + cur_g * 32 + o, acc);
            cur_g = g; acc = 0.f;
        }
        acc += v;
    }
    if (cur_g >= 0) atomicAdd(gsum + cur_g * 32 + o, acc);
}

// head: mean finalize + fc1 + fc2 + log_softmax
__global__ __launch_bounds__(256) void k8_head(const float* __restrict__ gsum,
        const int* __restrict__ batch,
        const float* __restrict__ fc1w, const float* __restrict__ fc1b,
        const float* __restrict__ fc2w, const float* __restrict__ fc2b,
        float* __restrict__ out) {
    __shared__ float gl[64][32];
    __shared__ float w1l[32][64];
    __shared__ float hl[64][64];
    __shared__ float zl[64][2];
    __shared__ float gc[64];
    int t = threadIdx.x;
    if (t < 64) {
        int g = t;
        int lo = 0, hi = N_NODES;
        while (lo < hi) { int mid = (lo + hi) >> 1; if (batch[mid] < g) lo = mid + 1; else hi = mid; }
        int s0 = lo;
        lo = 0; hi = N_NODES;
        while (lo < hi) { int mid = (lo + hi) >> 1; if (batch[mid] < g + 1) lo = mid + 1; else hi = mid; }
        gc[g] = fmaxf((float)(lo - s0), 1.0f);
    }
    for (int idx = t; idx < 32 * 64; idx += 256) w1l[idx >> 6][idx & 63] = fc1w[idx];
    __syncthreads();
    for (int idx = t; idx < 64 * 32; idx += 256) gl[idx >> 5][idx & 31] = gsum[idx] / gc[idx >> 5];
    __syncthreads();
    for (int idx = t; idx < 64 * 64; idx += 256) {
        int gg = idx >> 6, c = idx & 63;
        float acc = fc1b[c];
#pragma unroll
        for (int i = 0; i < 32; i++) acc += gl[gg][i] * w1l[i][c];
        hl[gg][c] = acc > 0.f ? acc : expm1f(acc);
    }
    __syncthreads();
    if (t < 128) {
        int gg = t >> 1, k = t & 1;
        float acc = fc2b[k];
#pragma unroll
        for (int c = 0; c < 64; c++) acc += hl[gg][c] * fc2w[c * 2 + k];
        zl[gg][k] = acc;
    }
    __syncthreads();
    if (t < 128) {
        int gg = t >> 1, k = t & 1;
        float z0 = zl[gg][0], z1 = zl[gg][1];
        float m = fmaxf(z0, z1);
        float lse = m + logf(expf(z0 - m) + expf(z1 - m));
        out[t] = zl[gg][k] - lse;
    }
}

extern "C" void kernel_launch(void* const* d_in, const int* in_sizes, int n_in,
                              void* d_out, int out_size, void* d_ws, size_t ws_size,
                              hipStream_t stream) {
    const float* x       = (const float*)d_in[0];
    const int*   ei      = (const int*)d_in[1];
    const float* ea      = (const float*)d_in[2];
    const int*   batch   = (const int*)d_in[3];
    const float* nn1_w1  = (const float*)d_in[4];
    const float* nn1_b1  = (const float*)d_in[5];
    const float* nn1_w2  = (const float*)d_in[6];
    const float* nn1_b2  = (const float*)d_in[7];
    const float* c1_root = (const float*)d_in[8];
    const float* c1_bias = (const float*)d_in[9];
    const float* nn2_w1  = (const float*)d_in[10];
    const float* nn2_b1  = (const float*)d_in[11];
    const float* nn2_w2  = (const float*)d_in[12];
    const float* nn2_b2  = (const float*)d_in[13];
    const float* c2_root = (const float*)d_in[14];
    const float* c2_bias = (const float*)d_in[15];
    const float* fc1w    = (const float*)d_in[16];
    const float* fc1b    = (const float*)d_in[17];
    const float* fc2w    = (const float*)d_in[18];
    const float* fc2b    = (const float*)d_in[19];
    const int* src = ei;
    const int* dst = ei + N_EDGES;

    char* ws = (char*)d_ws;
    size_t off = 0;
    __half2* tab1 = (__half2*)(ws + off); off += (size_t)N_NODES * 11 * 16 * 4;  // 35.2 MB
    __half2* tab2 = (__half2*)(ws + off); off += (size_t)N_NODES * 11 * 32 * 4;  // 70.4 MB
    float* R1   = (float*)(ws + off); off += (size_t)N_NODES * 16 * 4;
    float* R2   = (float*)(ws + off); off += (size_t)N_NODES * 32 * 4;
    float* h1   = (float*)(ws + off); off += (size_t)N_NODES * 16 * 4;
    float* h2   = (float*)(ws + off); off += (size_t)N_NODES * 32 * 4;
    int*   roff = (int*)(ws + off);   off += (size_t)N_NODES * 4;
    int*   woff = (int*)(ws + off);   off += (size_t)N_NODES * 4;
    int*   bsum = (int*)(ws + off);   off += (size_t)NSCAN_BLK * 4;
    int*   sse1 = (int*)(ws + off);   off += (size_t)N_EDGES * 4;
    int*   sse2 = (int*)(ws + off);   off += (size_t)N_EDGES * 4;
    float* sea  = (float*)(ws + off); off += (size_t)N_EDGES * 4;
    float* thrT = (float*)(ws + off); off += 20 * 4;
    int*   thrM = (int*)(ws + off);   off += 22 * 4;
    off = (off + 255) & ~(size_t)255;
    // ---- zeroed region (contiguous, one memset) ----
    char* zbase = ws + off;
    int*   cntd = (int*)(ws + off);   off += (size_t)N_NODES * 4;
    float* gsum = (float*)(ws + off); off += (size_t)NUM_GRAPHS * 32 * 4;
    size_t zbytes = (size_t)(ws + off - zbase);

    hipMemsetAsync(zbase, 0, zbytes, stream);

    k_thr<<<1, 64, 0, stream>>>(nn1_w1, nn1_b1, nn2_w1, nn2_b1, thrT, thrM);
    k0_hist<<<(N_EDGES + 255) / 256, 256, 0, stream>>>(dst, cntd);
    k0_scanA<<<NSCAN_BLK, 1024, 0, stream>>>(cntd, roff, woff, bsum);
    k0_scanB<<<NSCAN_BLK, 1024, 0, stream>>>(bsum, roff, woff);
    k0_scatter<<<(N_EDGES + 255) / 256, 256, 0, stream>>>(src, dst, ea, thrT, woff, sse1, sse2, sea);
    k1_p1<<<(N_NODES + 15) / 16, 256, 0, stream>>>(x, nn1_w2, nn1_b2, c1_root,
            nn1_w1, nn1_b1, c1_bias, thrM, tab1, R1);
    k2_edge1<<<(N_NODES + 15) / 16, 256, 0, stream>>>(tab1, roff, sse1, sea, R1, h1);
    k4_p2<<<(N_NODES + 7) / 8, 256, 0, stream>>>(h1, nn2_w2, nn2_b2, c2_root,
            nn2_w1, nn2_b1, c2_bias, thrM, tab2, R2);
    k5_edge2<<<(N_NODES + 7) / 8, 256, 0, stream>>>(tab2, roff, sse2, sea, R2, h2);
    k6_partial<<<512, 256, 0, stream>>>(h2, batch, gsum);
    k8_head<<<1, 256, 0, stream>>>(gsum, batch, fc1w, fc1b, fc2w, fc2b, (float*)d_out);
}

// Round 9
// 332.311 us; speedup vs baseline: 1.0077x; 1.0077x over previous
//
#include <hip/hip_runtime.h>
#include <hip/hip_fp16.h>
#include <math.h>

#define N_NODES 50000
#define N_EDGES 400000
#define NUM_GRAPHS 64
#define NSCAN_BLK ((N_NODES + 1023) / 1024)   // 49

// ---------------------------------------------------------------------------
// NNConv via piecewise-linear collapse + dst-CSR (atomic-free aggregation).
//   relu(a*w1_j+b1_j) is piecewise-linear in scalar a: <=11 intervals kappa.
//   msg[e,o] = a_e * A_k[src,o] + B_k[src,o]  (exact; A,B per node+interval)
// Tables are PLANE-MAJOR tab[kappa][n][o] (half2{A,B}); only planes actually
// used by >=1 edge are built/stored (usage mask from scatter pass). With
// b1==0 (this dataset) exactly one plane is used -> tables are L2-resident.
// Edges counting-sorted by dst; per-dst register accumulation, no atomics.
// ---------------------------------------------------------------------------

__global__ void k_thr(const float* __restrict__ w1a, const float* __restrict__ b1a,
                      const float* __restrict__ w1b, const float* __restrict__ b1b,
                      float* __restrict__ T, int* __restrict__ M) {
    if (threadIdx.x != 0 || blockIdx.x != 0) return;
    for (int layer = 0; layer < 2; layer++) {
        const float* w1 = layer ? w1b : w1a;
        const float* b1 = layer ? b1b : b1a;
        float t[10]; int idx[10];
        for (int j = 0; j < 10; j++) {
            float w = w1[j];
            t[j] = (w != 0.f) ? (-b1[j] / w) : INFINITY;
            idx[j] = j;
        }
        for (int i = 1; i < 10; i++) {
            float tv = t[i]; int iv = idx[i]; int k = i - 1;
            while (k >= 0 && t[k] > tv) { t[k + 1] = t[k]; idx[k + 1] = idx[k]; k--; }
            t[k + 1] = tv; idx[k + 1] = iv;
        }
        int pos[10];
        for (int k = 0; k < 10; k++) pos[idx[k]] = k;
        for (int k = 0; k < 10; k++) T[layer * 10 + k] = t[k];
        for (int kap = 0; kap <= 10; kap++) {
            int m = 0;
            for (int j = 0; j < 10; j++) {
                float w = w1[j];
                bool act = (w > 0.f) ? (pos[j] < kap)
                         : (w < 0.f) ? (pos[j] >= kap)
                         : (b1[j] > 0.f);
                if (act) m |= (1 << j);
            }
            M[layer * 11 + kap] = m;
        }
    }
}

__global__ __launch_bounds__(256) void k0_hist(const int* __restrict__ dst,
        int* __restrict__ cntd) {
    int e = blockIdx.x * 256 + threadIdx.x;
    if (e < N_EDGES) atomicAdd(cntd + dst[e], 1);
}

__global__ __launch_bounds__(1024) void k0_scanA(const int* __restrict__ cntd,
        int* __restrict__ roff, int* __restrict__ woff, int* __restrict__ bsum) {
    __shared__ int tmp[1024];
    int b = blockIdx.x, t = threadIdx.x;
    int n = b * 1024 + t;
    int v = (n < N_NODES) ? cntd[n] : 0;
    tmp[t] = v;
    __syncthreads();
    for (int off = 1; off < 1024; off <<= 1) {
        int add = (t >= off) ? tmp[t - off] : 0;
        __syncthreads();
        tmp[t] += add;
        __syncthreads();
    }
    if (n < N_NODES) { int ex = tmp[t] - v; roff[n] = ex; woff[n] = ex; }
    if (t == 1023) bsum[b] = tmp[1023];
}

__global__ __launch_bounds__(1024) void k0_scanB(const int* __restrict__ bsum,
        int* __restrict__ roff, int* __restrict__ woff) {
    __shared__ int boff;
    int b = blockIdx.x, t = threadIdx.x;
    if (t == 0) {
        int s = 0;
        for (int i = 0; i < b; i++) s += bsum[i];
        boff = s;
    }
    __syncthreads();
    int n = b * 1024 + t;
    if (n < N_NODES) { roff[n] += boff; woff[n] += boff; }
}

// scatter by dst; rows are PLANE-MAJOR (kappa*N + src); accumulate usage mask
__global__ __launch_bounds__(256) void k0_scatter(const int* __restrict__ src,
        const int* __restrict__ dst, const float* __restrict__ ea,
        const float* __restrict__ T, int* __restrict__ woff,
        int* __restrict__ sse1, int* __restrict__ sse2, float* __restrict__ sea,
        int* __restrict__ U) {
    __shared__ int um0, um1;
    int t = threadIdx.x;
    if (t == 0) { um0 = 0; um1 = 0; }
    __syncthreads();
    int e = blockIdx.x * 256 + t;
    if (e < N_EDGES) {
        int s = src[e], d = dst[e];
        float a = ea[e];
        int k1 = 0, k2 = 0;
#pragma unroll
        for (int j = 0; j < 10; j++) {
            k1 += (T[j] < a);
            k2 += (T[10 + j] < a);
        }
        int pos = atomicAdd(woff + d, 1);
        sse1[pos] = k1 * N_NODES + s;
        sse2[pos] = k2 * N_NODES + s;
        sea[pos] = a;
        atomicOr(&um0, 1 << k1);
        atomicOr(&um1, 1 << k2);
    }
    __syncthreads();
    if (t == 0) { atomicOr(U + 0, um0); atomicOr(U + 1, um1); }
}

// layer-1 node factors -> used planes of tab1[kap][n][16]; R1 = x@root+bias1
__global__ __launch_bounds__(256) void k1_p1(const float* __restrict__ x,
        const float* __restrict__ w2, const float* __restrict__ b2,
        const float* __restrict__ root, const float* __restrict__ w1,
        const float* __restrict__ b1, const float* __restrict__ bias1,
        const int* __restrict__ M, const int* __restrict__ U,
        __half2* __restrict__ tab1, float* __restrict__ R1) {
    __shared__ float Wl[32][192];   // [i][m*16+o]
    __shared__ float xl[16][32];
    __shared__ float w1l[10], b1l[10];
    __shared__ int ml[11];
    int t = threadIdx.x;
    for (int idx = t; idx < 32 * 192; idx += 256) {
        int i = idx / 192, c = idx % 192;
        int m = c >> 4, o = c & 15;
        float w;
        if (m < 10)       w = w2[m * 512 + i * 16 + o];
        else if (m == 10) w = b2[i * 16 + o];
        else              w = root[i * 16 + o];
        Wl[i][c] = w;
    }
    if (t < 10) { w1l[t] = w1[t]; b1l[t] = b1[t]; }
    if (t < 11) ml[t] = M[t];
    int n0 = blockIdx.x * 16;
    for (int idx = t; idx < 16 * 32; idx += 256) {
        int nl = idx >> 5, i = idx & 31;
        int n = n0 + nl;
        xl[nl][i] = (n < N_NODES) ? x[n * 32 + i] : 0.f;
    }
    __syncthreads();
    int used = U[0];
    int nl = t >> 4, o = t & 15;
    int n = n0 + nl;
    if (n >= N_NODES) return;
    float acc[12];
#pragma unroll
    for (int m = 0; m < 12; m++) acc[m] = 0.f;
#pragma unroll
    for (int i = 0; i < 32; i++) {
        float xv = xl[nl][i];
#pragma unroll
        for (int m = 0; m < 12; m++) acc[m] += xv * Wl[i][m * 16 + o];
    }
    // register-hoisted per-neuron terms; build only USED planes (static unroll)
    float wj[10], bj[10];
#pragma unroll
    for (int j = 0; j < 10; j++) { wj[j] = w1l[j] * acc[j]; bj[j] = b1l[j] * acc[j]; }
#pragma unroll
    for (int kap = 0; kap <= 10; kap++) {
        if ((used >> kap) & 1) {
            int m = ml[kap];
            float A = 0.f, B = acc[10];
#pragma unroll
            for (int j = 0; j < 10; j++) {
                if ((m >> j) & 1) { A += wj[j]; B += bj[j]; }
            }
            tab1[((size_t)kap * N_NODES + n) * 16 + o] = __floats2half2_rn(A, B);
        }
    }
    R1[n * 16 + o] = acc[11] + bias1[o];
}

// layer-1 edges (dst-CSR): 16 dst/block x 16 lanes; register accumulate, fused ELU
__global__ __launch_bounds__(256) void k2_edge1(const __half2* __restrict__ tab1,
        const int* __restrict__ roff, const int* __restrict__ sse1,
        const float* __restrict__ sea, const float* __restrict__ R1,
        float* __restrict__ h1) {
    int t = threadIdx.x;
    int d = blockIdx.x * 16 + (t >> 4);
    int o = t & 15;
    if (d >= N_NODES) return;
    int start = roff[d];
    int end = (d == N_NODES - 1) ? N_EDGES : roff[d + 1];
    float acc = 0.f;
    for (int p = start; p < end; ++p) {
        int row = sse1[p];
        float a = sea[p];
        float2 f = __half22float2(tab1[(size_t)row * 16 + o]);
        acc += a * f.x + f.y;
    }
    int deg = end - start;
    float c = (float)(deg > 0 ? deg : 1);
    float v = acc / c + R1[d * 16 + o];
    h1[d * 16 + o] = v > 0.f ? v : expm1f(v);
}

// layer-2 node factors from h1 -> used planes of tab2[kap][n][32]; R2 = h1@root+bias2
__global__ __launch_bounds__(256) void k4_p2(const float* __restrict__ h1,
        const float* __restrict__ w2, const float* __restrict__ b2,
        const float* __restrict__ root, const float* __restrict__ w1,
        const float* __restrict__ b1, const float* __restrict__ bias2,
        const int* __restrict__ M, const int* __restrict__ U,
        __half2* __restrict__ tab2, float* __restrict__ R2) {
    __shared__ float Wl[16][384];   // [i][m*32+o]
    __shared__ float hl[8][16];
    __shared__ float w1l[10], b1l[10];
    __shared__ int ml[11];
    int t = threadIdx.x;
    for (int idx = t; idx < 16 * 384; idx += 256) {
        int i = idx / 384, c = idx % 384;
        int m = c >> 5, o = c & 31;
        float w;
        if (m < 10)       w = w2[m * 512 + i * 32 + o];
        else if (m == 10) w = b2[i * 32 + o];
        else              w = root[i * 32 + o];
        Wl[i][c] = w;
    }
    if (t < 10) { w1l[t] = w1[t]; b1l[t] = b1[t]; }
    if (t < 11) ml[t] = M[11 + t];
    int n0 = blockIdx.x * 8;
    if (t < 128) {
        int nl = t >> 4, i = t & 15;
        int n = n0 + nl;
        hl[nl][i] = (n < N_NODES) ? h1[n * 16 + i] : 0.f;
    }
    __syncthreads();
    int used = U[1];
    int nl = t >> 5, o = t & 31;
    int n = n0 + nl;
    if (n >= N_NODES) return;
    float acc[12];
#pragma unroll
    for (int m = 0; m < 12; m++) acc[m] = 0.f;
#pragma unroll
    for (int i = 0; i < 16; i++) {
        float hv = hl[nl][i];
#pragma unroll
        for (int m = 0; m < 12; m++) acc[m] += hv * Wl[i][m * 32 + o];
    }
    float wj[10], bj[10];
#pragma unroll
    for (int j = 0; j < 10; j++) { wj[j] = w1l[j] * acc[j]; bj[j] = b1l[j] * acc[j]; }
#pragma unroll
    for (int kap = 0; kap <= 10; kap++) {
        if ((used >> kap) & 1) {
            int m = ml[kap];
            float A = 0.f, B = acc[10];
#pragma unroll
            for (int j = 0; j < 10; j++) {
                if ((m >> j) & 1) { A += wj[j]; B += bj[j]; }
            }
            tab2[((size_t)kap * N_NODES + n) * 32 + o] = __floats2half2_rn(A, B);
        }
    }
    R2[(size_t)n * 32 + o] = acc[11] + bias2[o];
}

// layer-2 edges (dst-CSR): 8 dst/block x 32 lanes; fused ELU -> h2
__global__ __launch_bounds__(256) void k5_edge2(const __half2* __restrict__ tab2,
        const int* __restrict__ roff, const int* __restrict__ sse2,
        const float* __restrict__ sea, const float* __restrict__ R2,
        float* __restrict__ h2) {
    int t = threadIdx.x;
    int d = blockIdx.x * 8 + (t >> 5);
    int o = t & 31;
    if (d >= N_NODES) return;
    int start = roff[d];
    int end = (d == N_NODES - 1) ? N_EDGES : roff[d + 1];
    float acc = 0.f;
    for (int p = start; p < end; ++p) {
        int row = sse2[p];
        float a = sea[p];
        float2 f = __half22float2(tab2[(size_t)row * 32 + o]);
        acc += a * f.x + f.y;
    }
    int deg = end - start;
    float c = (float)(deg > 0 ? deg : 1);
    float v = acc / c + R2[(size_t)d * 32 + o];
    h2[(size_t)d * 32 + o] = v > 0.f ? v : expm1f(v);
}

// pooling partials: 512 blocks, register accumulate per graph run
__global__ __launch_bounds__(256) void k6_partial(const float* __restrict__ h2,
        const int* __restrict__ batch, float* __restrict__ gsum) {
    const int NB = 512;
    const int chunk = (N_NODES + NB - 1) / NB;   // 98
    int begin = blockIdx.x * chunk;
    int end = begin + chunk;
    if (end > N_NODES) end = N_NODES;
    int t = threadIdx.x;
    int o = t & 31, ch = t >> 5;
    float acc = 0.f;
    int cur_g = -1;
    for (int n = begin + ch; n < end; n += 8) {
        int g = batch[n];
        float v = h2[(size_t)n * 32 + o];
        if (g != cur_g) {
            if (cur_g >= 0) atomicAdd(gsum + cur_g * 32 + o, acc);
            cur_g = g; acc = 0.f;
        }
        acc += v;
    }
    if (cur_g >= 0) atomicAdd(gsum + cur_g * 32 + o, acc);
}

// head: mean finalize + fc1 + fc2 + log_softmax
__global__ __launch_bounds__(256) void k8_head(const float* __restrict__ gsum,
        const int* __restrict__ batch,
        const float* __restrict__ fc1w, const float* __restrict__ fc1b,
        const float* __restrict__ fc2w, const float* __restrict__ fc2b,
        float* __restrict__ out) {
    __shared__ float gl[64][32];
    __shared__ float w1l[32][64];
    __shared__ float hl[64][64];
    __shared__ float zl[64][2];
    __shared__ float gc[64];
    int t = threadIdx.x;
    if (t < 64) {
        int g = t;
        int lo = 0, hi = N_NODES;
        while (lo < hi) { int mid = (lo + hi) >> 1; if (batch[mid] < g) lo = mid + 1; else hi = mid; }
        int s0 = lo;
        lo = 0; hi = N_NODES;
        while (lo < hi) { int mid = (lo + hi) >> 1; if (batch[mid] < g + 1) lo = mid + 1; else hi = mid; }
        gc[g] = fmaxf((float)(lo - s0), 1.0f);
    }
    for (int idx = t; idx < 32 * 64; idx += 256) w1l[idx >> 6][idx & 63] = fc1w[idx];
    __syncthreads();
    for (int idx = t; idx < 64 * 32; idx += 256) gl[idx >> 5][idx & 31] = gsum[idx] / gc[idx >> 5];
    __syncthreads();
    for (int idx = t; idx < 64 * 64; idx += 256) {
        int gg = idx >> 6, c = idx & 63;
        float acc = fc1b[c];
#pragma unroll
        for (int i = 0; i < 32; i++) acc += gl[gg][i] * w1l[i][c];
        hl[gg][c] = acc > 0.f ? acc : expm1f(acc);
    }
    __syncthreads();
    if (t < 128) {
        int gg = t >> 1, k = t & 1;
        float acc = fc2b[k];
#pragma unroll
        for (int c = 0; c < 64; c++) acc += hl[gg][c] * fc2w[c * 2 + k];
        zl[gg][k] = acc;
    }
    __syncthreads();
    if (t < 128) {
        int gg = t >> 1, k = t & 1;
        float z0 = zl[gg][0], z1 = zl[gg][1];
        float m = fmaxf(z0, z1);
        float lse = m + logf(expf(z0 - m) + expf(z1 - m));
        out[t] = zl[gg][k] - lse;
    }
}

extern "C" void kernel_launch(void* const* d_in, const int* in_sizes, int n_in,
                              void* d_out, int out_size, void* d_ws, size_t ws_size,
                              hipStream_t stream) {
    const float* x       = (const float*)d_in[0];
    const int*   ei      = (const int*)d_in[1];
    const float* ea      = (const float*)d_in[2];
    const int*   batch   = (const int*)d_in[3];
    const float* nn1_w1  = (const float*)d_in[4];
    const float* nn1_b1  = (const float*)d_in[5];
    const float* nn1_w2  = (const float*)d_in[6];
    const float* nn1_b2  = (const float*)d_in[7];
    const float* c1_root = (const float*)d_in[8];
    const float* c1_bias = (const float*)d_in[9];
    const float* nn2_w1  = (const float*)d_in[10];
    const float* nn2_b1  = (const float*)d_in[11];
    const float* nn2_w2  = (const float*)d_in[12];
    const float* nn2_b2  = (const float*)d_in[13];
    const float* c2_root = (const float*)d_in[14];
    const float* c2_bias = (const float*)d_in[15];
    const float* fc1w    = (const float*)d_in[16];
    const float* fc1b    = (const float*)d_in[17];
    const float* fc2w    = (const float*)d_in[18];
    const float* fc2b    = (const float*)d_in[19];
    const int* src = ei;
    const int* dst = ei + N_EDGES;

    char* ws = (char*)d_ws;
    size_t off = 0;
    __half2* tab1 = (__half2*)(ws + off); off += (size_t)N_NODES * 11 * 16 * 4;  // 35.2 MB
    __half2* tab2 = (__half2*)(ws + off); off += (size_t)N_NODES * 11 * 32 * 4;  // 70.4 MB
    float* R1   = (float*)(ws + off); off += (size_t)N_NODES * 16 * 4;
    float* R2   = (float*)(ws + off); off += (size_t)N_NODES * 32 * 4;
    float* h1   = (float*)(ws + off); off += (size_t)N_NODES * 16 * 4;
    float* h2   = (float*)(ws + off); off += (size_t)N_NODES * 32 * 4;
    int*   roff = (int*)(ws + off);   off += (size_t)N_NODES * 4;
    int*   woff = (int*)(ws + off);   off += (size_t)N_NODES * 4;
    int*   bsum = (int*)(ws + off);   off += (size_t)NSCAN_BLK * 4;
    int*   sse1 = (int*)(ws + off);   off += (size_t)N_EDGES * 4;
    int*   sse2 = (int*)(ws + off);   off += (size_t)N_EDGES * 4;
    float* sea  = (float*)(ws + off); off += (size_t)N_EDGES * 4;
    float* thrT = (float*)(ws + off); off += 20 * 4;
    int*   thrM = (int*)(ws + off);   off += 22 * 4;
    off = (off + 255) & ~(size_t)255;
    // ---- zeroed region (contiguous, one memset) ----
    char* zbase = ws + off;
    int*   cntd = (int*)(ws + off);   off += (size_t)N_NODES * 4;
    float* gsum = (float*)(ws + off); off += (size_t)NUM_GRAPHS * 32 * 4;
    int*   thrU = (int*)(ws + off);   off += 2 * 4;
    size_t zbytes = (size_t)(ws + off - zbase);

    hipMemsetAsync(zbase, 0, zbytes, stream);

    k_thr<<<1, 64, 0, stream>>>(nn1_w1, nn1_b1, nn2_w1, nn2_b1, thrT, thrM);
    k0_hist<<<(N_EDGES + 255) / 256, 256, 0, stream>>>(dst, cntd);
    k0_scanA<<<NSCAN_BLK, 1024, 0, stream>>>(cntd, roff, woff, bsum);
    k0_scanB<<<NSCAN_BLK, 1024, 0, stream>>>(bsum, roff, woff);
    k0_scatter<<<(N_EDGES + 255) / 256, 256, 0, stream>>>(src, dst, ea, thrT, woff,
            sse1, sse2, sea, thrU);
    k1_p1<<<(N_NODES + 15) / 16, 256, 0, stream>>>(x, nn1_w2, nn1_b2, c1_root,
            nn1_w1, nn1_b1, c1_bias, thrM, thrU, tab1, R1);
    k2_edge1<<<(N_NODES + 15) / 16, 256, 0, stream>>>(tab1, roff, sse1, sea, R1, h1);
    k4_p2<<<(N_NODES + 7) / 8, 256, 0, stream>>>(h1, nn2_w2, nn2_b2, c2_root,
            nn2_w1, nn2_b1, c2_bias, thrM, thrU, tab2, R2);
    k5_edge2<<<(N_NODES + 7) / 8, 256, 0, stream>>>(tab2, roff, sse2, sea, R2, h2);
    k6_partial<<<512, 256, 0, stream>>>(h2, batch, gsum);
    k8_head<<<1, 256, 0, stream>>>(gsum, batch, fc1w, fc1b, fc2w, fc2b, (float*)d_out);
}